// Round 19
// baseline (124.780 us; speedup 1.0000x reference)
//
#include <hip/hip_runtime.h>

// ConcatenationAttention: B=8, S=1024, H=128, A=16
// out[b,i,:] = sum_{j<i} w_ij * x[b,j,:],  w = softmax over j of
//   score(i,j) = sum_a w2[a]*tanh(f[b,i,a] + g[b,j,a] + b1[a]) + b2
//
// Round 19: one tile per block, 512 threads (8 waves), 512 blocks ->
// 4 blocks/CU, 8 waves/SIMD (2x latency hiding vs r18's 1024-thread blocks).
// Phase 1: wave wv computes chunks wv, wv+8 of its tile. Phase 2: wave wv
// owns cols [wv*16,+16) of the tile, MFMA numerator + ones-MFMA denominator.
// Block order pairs tile 63-u with tile u per CU (nch sums ~17, balanced).

#define B_ 8
#define S_ 1024
#define H_ 128
#define A_ 16

typedef float f32x4v __attribute__((ext_vector_type(4)));
typedef short bf16x8 __attribute__((ext_vector_type(8)));

__device__ __forceinline__ unsigned short bf16_rne(float v) {
  unsigned u = __float_as_uint(v);
  u += 0x7FFFu + ((u >> 16) & 1u);
  return (unsigned short)(u >> 16);
}

// Fused prep: f/g projection (exp2 domain) + xfrag bf16 B-fragment packing.
__global__ __launch_bounds__(256) void prep_kernel(
    const float* __restrict__ x, const float* __restrict__ W1,
    const float* __restrict__ b1, float* __restrict__ f2,
    float* __restrict__ g2, unsigned short* __restrict__ xfrag) {
  __shared__ __align__(16) float xls[8 * H_];  // 4 KB
  const int tid = threadIdx.x;
  const int row0 = blockIdx.x * 8;
  reinterpret_cast<float4*>(xls)[tid] =
      reinterpret_cast<const float4*>(x + (size_t)row0 * H_)[tid];
  __syncthreads();

  // ---- f/g: 8 rows x 32 (16 a x 2 half) ----
  {
    const int r = tid >> 5;
    const int q = tid & 31;
    const int a = q & 15;
    const int half = q >> 4;
    const float4* xr4 = reinterpret_cast<const float4*>(xls + r * H_);
    const float* w = W1 + half * H_ * A_ + a;
    float s = 0.f;
#pragma unroll 4
    for (int hi = 0; hi < H_ / 4; ++hi) {
      float4 xv = xr4[hi];
      s = fmaf(xv.x, w[(hi * 4 + 0) * A_], s);
      s = fmaf(xv.y, w[(hi * 4 + 1) * A_], s);
      s = fmaf(xv.z, w[(hi * 4 + 2) * A_], s);
      s = fmaf(xv.w, w[(hi * 4 + 3) * A_], s);
    }
    const float TANH_C = 2.8853900817779268f;   // 2*log2(e)
    const int row = row0 + r;
    if (half == 0)
      f2[row * A_ + a] = __builtin_amdgcn_exp2f((s + b1[a]) * TANH_C);
    else
      g2[row * A_ + a] = __builtin_amdgcn_exp2f(s * TANH_C);
  }

  // ---- xfrag: threads 0..127 pack col (nt*16+li) of all 8 rows ----
  if (tid < 128) {
    const int nt = tid >> 4;
    const int li = tid & 15;
    const int col = (nt << 4) + li;
    const int b = row0 >> 10;
    const int j0 = row0 & 1023;
    const int jt = j0 >> 5;
    const int sub = (j0 >> 3) & 3;
    union { unsigned short u[8]; uint4 v; } rr;
#pragma unroll
    for (int e = 0; e < 8; ++e) rr.u[e] = bf16_rne(xls[e * H_ + col]);
    reinterpret_cast<uint4*>(
        xfrag)[(((size_t)((b << 5) + jt) * 8 + nt) << 6) + (sub << 4) + li] =
        rr.v;
  }
}

// -------- round 19: one tile per 512-thread block, 8 waves/SIMD ------------
__global__ __launch_bounds__(512, 8) void attn_fused6(
    const float* __restrict__ f2, const float* __restrict__ g2,
    const unsigned short* __restrict__ xfrag, const float* __restrict__ w2,
    const float* __restrict__ b2, float* __restrict__ out) {
  __shared__ __align__(16) unsigned short esb[16][1024];  // 32 KB
  __shared__ __align__(16) float f_lds[256];              // 1 KB

  const int tid = threadIdx.x;
  const int wv = tid >> 6;       // [0,8)
  const int lane = tid & 63;
  const int bid = blockIdx.x;
  // pairing order: bids [0,256) -> tiles 63..32 (heavy), [256,512) -> 0..31
  const int t = (bid < 256) ? (63 - (bid >> 3)) : ((bid - 256) >> 3);
  const int b = bid & 7;
  const int nch = (t >> 2) + 1;
  const int i0 = t << 4;

  // ---- hoisted g load for first chunk (cc = wv) ----
  const float4* gpA = reinterpret_cast<const float4*>(
      g2 + ((size_t)((b << 10) + (wv << 6) + lane) << 4));
  float4 gA0 = gpA[0], gA1 = gpA[1], gA2 = gpA[2], gA3 = gpA[3];

  // ---- stage f-tile into LDS (256 floats) ----
  if (tid < 256)
    f_lds[tid] = f2[(((size_t)(b << 10) + (t << 4)) << 4) + tid];
  __syncthreads();

  const float LOG2E = 1.4426950408889634f;
  float w2s[16];
  float K;
  {
    float sw = 0.f;
#pragma unroll
    for (int a = 0; a < 16; ++a) {
      float v = w2[a];
      w2s[a] = v * (2.f * LOG2E);
      sw += v;
    }
    K = (sw + b2[0]) * LOG2E;
  }
  const float4* fl4 = reinterpret_cast<const float4*>(&f_lds[0]);

  // ---- phase 1: wave wv computes chunks wv, wv+8 (if < nch) ----
  for (int cc = wv; cc < nch; cc += 8) {
    float gr[16];
    if (cc == wv) {
      gr[0] = gA0.x;  gr[1] = gA0.y;  gr[2] = gA0.z;  gr[3] = gA0.w;
      gr[4] = gA1.x;  gr[5] = gA1.y;  gr[6] = gA1.z;  gr[7] = gA1.w;
      gr[8] = gA2.x;  gr[9] = gA2.y;  gr[10] = gA2.z; gr[11] = gA2.w;
      gr[12] = gA3.x; gr[13] = gA3.y; gr[14] = gA3.z; gr[15] = gA3.w;
    } else {
      const float4* gp = reinterpret_cast<const float4*>(
          g2 + ((size_t)((b << 10) + (cc << 6) + lane) << 4));
      float4 g0 = gp[0], g1 = gp[1], g2v = gp[2], g3 = gp[3];
      gr[0] = g0.x;  gr[1] = g0.y;  gr[2] = g0.z;  gr[3] = g0.w;
      gr[4] = g1.x;  gr[5] = g1.y;  gr[6] = g1.z;  gr[7] = g1.w;
      gr[8] = g2v.x; gr[9] = g2v.y; gr[10] = g2v.z; gr[11] = g2v.w;
      gr[12] = g3.x; gr[13] = g3.y; gr[14] = g3.z; gr[15] = g3.w;
    }
    char* esbase = reinterpret_cast<char*>(&esb[cc][0]);
    const int jglob = (cc << 6) + lane;
    const int jx2 = lane << 1;
#pragma unroll
    for (int i = 0; i < 16; ++i) {
      float4 fa = fl4[(i << 2) + 0], fb = fl4[(i << 2) + 1];
      float4 fc = fl4[(i << 2) + 2], fd = fl4[(i << 2) + 3];
      float frv[16] = {fa.x, fa.y, fa.z, fa.w, fb.x, fb.y, fb.z, fb.w,
                       fc.x, fc.y, fc.z, fc.w, fd.x, fd.y, fd.z, fd.w};
      float ps0 = 0.f, ps1 = 0.f;
#define TERM(idx, dst)                                                   \
  dst = fmaf(w2s[idx],                                                   \
             __builtin_amdgcn_rcpf(fmaf(frv[idx], gr[idx], 1.0f)),       \
             dst);
      TERM(0, ps0)  TERM(1, ps0)  TERM(2, ps0)  TERM(3, ps0)
      TERM(4, ps0)  TERM(5, ps0)  TERM(6, ps0)  TERM(7, ps0)
      TERM(8, ps1)  TERM(9, ps1)  TERM(10, ps1) TERM(11, ps1)
      TERM(12, ps1) TERM(13, ps1) TERM(14, ps1) TERM(15, ps1)
#undef TERM
      float ev =
          (jglob < i0 + i) ? __builtin_amdgcn_exp2f(K - (ps0 + ps1)) : 0.f;
      *reinterpret_cast<unsigned short*>(
          esbase + (((i << 7) + jx2) ^ ((i & 7) << 4))) = bf16_rne(ev);
    }
  }
  __syncthreads();  // all nch e tiles visible

  // ---- phase 2: wave wv owns cols [wv*16,+16) of the tile ----
  {
    const int nt = wv;
    const int li = lane & 15;
    const int g = lane >> 4;
    const int cxor = (li & 7) << 4;
    const int off0 = ((li << 7) + (g << 4)) ^ cxor;       // k-tile 0 (j 0..31)
    const int off1 = ((li << 7) + 64 + (g << 4)) ^ cxor;  // k-tile 1 (j 32..63)

    f32x4v acc = (f32x4v){0.f, 0.f, 0.f, 0.f};
    f32x4v accD = (f32x4v){0.f, 0.f, 0.f, 0.f};
    bf16x8 ones;
#pragma unroll
    for (int e = 0; e < 8; ++e) ones[e] = (short)0x3F80;  // bf16(1.0)

    const bf16x8* xfb =
        reinterpret_cast<const bf16x8*>(xfrag) + ((size_t)(b << 5) << 9) + lane;
    for (int cc = 0; cc < nch; ++cc) {
      const char* eb = reinterpret_cast<const char*>(&esb[cc][0]);
      bf16x8 a0 = *reinterpret_cast<const bf16x8*>(eb + off0);
      bf16x8 a1 = *reinterpret_cast<const bf16x8*>(eb + off1);
      const bf16x8* xf = xfb + ((size_t)(cc << 1) << 9);
      bf16x8 bf0 = xf[(size_t)(nt << 6)];
      bf16x8 bf1 = xf[(size_t)(nt << 6) + 512];
      acc = __builtin_amdgcn_mfma_f32_16x16x32_bf16(a0, bf0, acc, 0, 0, 0);
      acc = __builtin_amdgcn_mfma_f32_16x16x32_bf16(a1, bf1, acc, 0, 0, 0);
      accD = __builtin_amdgcn_mfma_f32_16x16x32_bf16(a0, ones, accD, 0, 0, 0);
      accD = __builtin_amdgcn_mfma_f32_16x16x32_bf16(a1, ones, accD, 0, 0, 0);
    }

    float* op = out + ((size_t)((b << 10) + (t << 4)) << 7) + (nt << 4) + li;
#pragma unroll
    for (int rr = 0; rr < 4; ++rr)
      op[(size_t)((g << 2) + rr) << 7] = acc[rr] / (accD[rr] + 1e-10f);
  }
}

// ---------------- fallback: monolithic kernel (factorized math) ------------
#define JC 64
__global__ __launch_bounds__(256) void attn_kernel_mono(
    const float* __restrict__ x, const float* __restrict__ f2,
    const float* __restrict__ g2, const float* __restrict__ w2,
    const float* __restrict__ b2, float* __restrict__ out) {
  __shared__ __align__(16) float xs[JC * H_];
  __shared__ __align__(16) float gsm[JC * 18];
  __shared__ __align__(16) float es2[JC * A_];
  __shared__ float dpart[4][16];
  __shared__ float denom[16];

  const int tid = threadIdx.x;
  const int bid = blockIdx.x;
  const int tile = 63 - (bid >> 3);
  const int b = bid & 7;
  const int i0 = tile * 16;

  const float LOG2E = 1.4426950408889634f;
  float w2s[16];
  float K;
  {
    float sw = 0.f;
#pragma unroll
    for (int a = 0; a < 16; ++a) {
      float v = w2[a];
      w2s[a] = v * (2.f * LOG2E);
      sw += v;
    }
    K = (sw + b2[0]) * LOG2E;
  }

  const int ti_e = tid & 15;
  const int jq = tid >> 4;
  float f_reg[16];
  {
    const float* frow = f2 + (size_t)((b << 10) + i0 + ti_e) * A_;
#pragma unroll
    for (int a = 0; a < 16; ++a) f_reg[a] = frow[a];
  }

  const int hc = tid & 31;
  const int jg = tid >> 5;
  float4 acc[16];
#pragma unroll
  for (int t = 0; t < 16; ++t) acc[t] = make_float4(0.f, 0.f, 0.f, 0.f);
  if (tid < 16) denom[tid] = 0.f;

  const int nch = (i0 + 15 + JC - 1) / JC;
  float4* xs4 = reinterpret_cast<float4*>(xs);
  const float4* es4 = reinterpret_cast<const float4*>(es2);
  const float4* xg4 = reinterpret_cast<const float4*>(x + (size_t)(b << 10) * H_);

  for (int c = 0; c < nch; ++c) {
    const int jbase = c * JC;
    __syncthreads();
    const float4* src = xg4 + jbase * (H_ / 4);
#pragma unroll
    for (int t = 0; t < 8; ++t) xs4[tid + 256 * t] = src[tid + 256 * t];
    {
      const float4* g4p =
          reinterpret_cast<const float4*>(g2 + (size_t)((b << 10) + jbase) * A_);
      float4 g4 = g4p[tid];
      float* dst = gsm + (tid >> 2) * 18 + (tid & 3) * 4;
      dst[0] = g4.x; dst[1] = g4.y; dst[2] = g4.z; dst[3] = g4.w;
    }
    __syncthreads();

    float partial = 0.f;
#pragma unroll
    for (int k = 0; k < 4; ++k) {
      const int jl = jq * 4 + k;
      const int j = jbase + jl;
      const float* grow = gsm + jl * 18;
      float ps = 0.f;
#pragma unroll
      for (int a = 0; a < 16; ++a) {
        float rr = __builtin_amdgcn_rcpf(fmaf(f_reg[a], grow[a], 1.0f));
        ps = fmaf(w2s[a], rr, ps);
      }
      float ev = (j < i0 + ti_e) ? __builtin_amdgcn_exp2f(K - ps) : 0.f;
      es2[jl * A_ + ti_e] = ev;
      partial += ev;
    }
    partial += __shfl_xor(partial, 16);
    partial += __shfl_xor(partial, 32);
    if ((tid & 63) < 16) dpart[tid >> 6][ti_e] = partial;
    __syncthreads();
    if (tid < 16)
      denom[tid] += dpart[0][tid] + dpart[1][tid] + dpart[2][tid] + dpart[3][tid];

#pragma unroll 2
    for (int jj = 0; jj < 8; ++jj) {
      const int jl = jg * 8 + jj;
      float4 xv = xs4[jl * (H_ / 4) + hc];
      float4 e0 = es4[jl * 4 + 0];
      float4 e1 = es4[jl * 4 + 1];
      float4 e2v = es4[jl * 4 + 2];
      float4 e3 = es4[jl * 4 + 3];
#define FMA4_(AC, sc)                \
  AC.x = fmaf(sc, xv.x, AC.x);       \
  AC.y = fmaf(sc, xv.y, AC.y);       \
  AC.z = fmaf(sc, xv.z, AC.z);       \
  AC.w = fmaf(sc, xv.w, AC.w)
      FMA4_(acc[0], e0.x);  FMA4_(acc[1], e0.y);
      FMA4_(acc[2], e0.z);  FMA4_(acc[3], e0.w);
      FMA4_(acc[4], e1.x);  FMA4_(acc[5], e1.y);
      FMA4_(acc[6], e1.z);  FMA4_(acc[7], e1.w);
      FMA4_(acc[8], e2v.x); FMA4_(acc[9], e2v.y);
      FMA4_(acc[10], e2v.z); FMA4_(acc[11], e2v.w);
      FMA4_(acc[12], e3.x); FMA4_(acc[13], e3.y);
      FMA4_(acc[14], e3.z); FMA4_(acc[15], e3.w);
#undef FMA4_
    }
  }

  __syncthreads();
  float4* red4 = xs4;
  if (jg >= 4) {
#pragma unroll
    for (int t = 0; t < 16; ++t) red4[((jg - 4) * 16 + t) * 32 + hc] = acc[t];
  }
  __syncthreads();
  if (jg < 4) {
#pragma unroll
    for (int t = 0; t < 16; ++t) {
      float4 v = red4[(jg * 16 + t) * 32 + hc];
      acc[t].x += v.x; acc[t].y += v.y; acc[t].z += v.z; acc[t].w += v.w;
    }
  }
  __syncthreads();
  if (jg == 2 || jg == 3) {
#pragma unroll
    for (int t = 0; t < 16; ++t) red4[((jg - 2) * 16 + t) * 32 + hc] = acc[t];
  }
  __syncthreads();
  if (jg < 2) {
#pragma unroll
    for (int t = 0; t < 16; ++t) {
      float4 v = red4[(jg * 16 + t) * 32 + hc];
      acc[t].x += v.x; acc[t].y += v.y; acc[t].z += v.z; acc[t].w += v.w;
    }
  }
  __syncthreads();
  if (jg == 1) {
#pragma unroll
    for (int t = 0; t < 16; ++t) red4[t * 32 + hc] = acc[t];
  }
  __syncthreads();
  if (jg == 0) {
    float4* out4 = reinterpret_cast<float4*>(out);
#pragma unroll
    for (int t = 0; t < 16; ++t) {
      float4 v = red4[t * 32 + hc];
      float dn = 1.0f / (denom[t] + 1e-10f);
      float4 o;
      o.x = (acc[t].x + v.x) * dn;
      o.y = (acc[t].y + v.y) * dn;
      o.z = (acc[t].z + v.z) * dn;
      o.w = (acc[t].w + v.w) * dn;
      out4[(size_t)((b << 10) + i0 + t) * 32 + hc] = o;
    }
  }
}

extern "C" void kernel_launch(void* const* d_in, const int* in_sizes, int n_in,
                              void* d_out, int out_size, void* d_ws,
                              size_t ws_size, hipStream_t stream) {
  (void)in_sizes; (void)n_in; (void)out_size;
  const float* x  = (const float*)d_in[0];
  const float* W1 = (const float*)d_in[1];
  const float* b1 = (const float*)d_in[2];
  const float* w2 = (const float*)d_in[3];
  const float* b2 = (const float*)d_in[4];
  float* out = (float*)d_out;

  float* f2 = (float*)d_ws;                  // [B*S, A]  F = exp2 domain
  float* g2 = f2 + (size_t)B_ * S_ * A_;     // [B*S, A]  E = exp2 domain
  unsigned short* xfrag = (unsigned short*)(g2 + (size_t)B_ * S_ * A_);

  const size_t need_fused =
      ((size_t)B_ * S_ * A_ * 2 + 524288 /*xfrag as float-equivalents*/) *
      sizeof(float);

  if (ws_size >= need_fused) {
    prep_kernel<<<B_ * S_ / 8, 256, 0, stream>>>(x, W1, b1, f2, g2, xfrag);
    attn_fused6<<<512, 512, 0, stream>>>(f2, g2, xfrag, w2, b2, out);
  } else {
    prep_kernel<<<B_ * S_ / 8, 256, 0, stream>>>(x, W1, b1, f2, g2,
                                                 (unsigned short*)f2 /*dummy*/);
    attn_kernel_mono<<<B_ * 64, 256, 0, stream>>>(x, f2, g2, w2, b2, out);
  }
}

// Round 20
// 77.891 us; speedup vs baseline: 1.6020x; 1.6020x over previous
//
#include <hip/hip_runtime.h>

// ConcatenationAttention: B=8, S=1024, H=128, A=16
// out[b,i,:] = sum_{j<i} w_ij * x[b,j,:],  w = softmax over j of
//   score(i,j) = sum_a w2[a]*tanh(f[b,i,a] + g[b,j,a] + b1[a]) + b2
//
// Round 20: r19 structure (one tile / 512-thread block, 512 blocks) with the
// register cap FIXED: __launch_bounds__(512,4) -> VGPR cap 128, no spill
// (r19's (512,8) cap=64 spilled ~380MB scratch). 2 independent blocks/CU.
// g loads back inside the loop (no long live ranges).

#define B_ 8
#define S_ 1024
#define H_ 128
#define A_ 16

typedef float f32x4v __attribute__((ext_vector_type(4)));
typedef short bf16x8 __attribute__((ext_vector_type(8)));

__device__ __forceinline__ unsigned short bf16_rne(float v) {
  unsigned u = __float_as_uint(v);
  u += 0x7FFFu + ((u >> 16) & 1u);
  return (unsigned short)(u >> 16);
}

// Fused prep: f/g projection (exp2 domain) + xfrag bf16 B-fragment packing.
__global__ __launch_bounds__(256) void prep_kernel(
    const float* __restrict__ x, const float* __restrict__ W1,
    const float* __restrict__ b1, float* __restrict__ f2,
    float* __restrict__ g2, unsigned short* __restrict__ xfrag) {
  __shared__ __align__(16) float xls[8 * H_];  // 4 KB
  const int tid = threadIdx.x;
  const int row0 = blockIdx.x * 8;
  reinterpret_cast<float4*>(xls)[tid] =
      reinterpret_cast<const float4*>(x + (size_t)row0 * H_)[tid];
  __syncthreads();

  // ---- f/g: 8 rows x 32 (16 a x 2 half) ----
  {
    const int r = tid >> 5;
    const int q = tid & 31;
    const int a = q & 15;
    const int half = q >> 4;
    const float4* xr4 = reinterpret_cast<const float4*>(xls + r * H_);
    const float* w = W1 + half * H_ * A_ + a;
    float s = 0.f;
#pragma unroll 4
    for (int hi = 0; hi < H_ / 4; ++hi) {
      float4 xv = xr4[hi];
      s = fmaf(xv.x, w[(hi * 4 + 0) * A_], s);
      s = fmaf(xv.y, w[(hi * 4 + 1) * A_], s);
      s = fmaf(xv.z, w[(hi * 4 + 2) * A_], s);
      s = fmaf(xv.w, w[(hi * 4 + 3) * A_], s);
    }
    const float TANH_C = 2.8853900817779268f;   // 2*log2(e)
    const int row = row0 + r;
    if (half == 0)
      f2[row * A_ + a] = __builtin_amdgcn_exp2f((s + b1[a]) * TANH_C);
    else
      g2[row * A_ + a] = __builtin_amdgcn_exp2f(s * TANH_C);
  }

  // ---- xfrag: threads 0..127 pack col (nt*16+li) of all 8 rows ----
  if (tid < 128) {
    const int nt = tid >> 4;
    const int li = tid & 15;
    const int col = (nt << 4) + li;
    const int b = row0 >> 10;
    const int j0 = row0 & 1023;
    const int jt = j0 >> 5;
    const int sub = (j0 >> 3) & 3;
    union { unsigned short u[8]; uint4 v; } rr;
#pragma unroll
    for (int e = 0; e < 8; ++e) rr.u[e] = bf16_rne(xls[e * H_ + col]);
    reinterpret_cast<uint4*>(
        xfrag)[(((size_t)((b << 5) + jt) * 8 + nt) << 6) + (sub << 4) + li] =
        rr.v;
  }
}

// -------- round 20: one tile / 512-thread block, NO register cap -----------
__global__ __launch_bounds__(512, 4) void attn_fused7(
    const float* __restrict__ f2, const float* __restrict__ g2,
    const unsigned short* __restrict__ xfrag, const float* __restrict__ w2,
    const float* __restrict__ b2, float* __restrict__ out) {
  __shared__ __align__(16) unsigned short esb[16][1024];  // 32 KB
  __shared__ __align__(16) float f_lds[256];              // 1 KB

  const int tid = threadIdx.x;
  const int wv = tid >> 6;       // [0,8)
  const int lane = tid & 63;
  const int bid = blockIdx.x;
  // pairing order: bids [0,256) -> tiles 63..32 (heavy), [256,512) -> 0..31
  const int t = (bid < 256) ? (63 - (bid >> 3)) : ((bid - 256) >> 3);
  const int b = bid & 7;
  const int nch = (t >> 2) + 1;
  const int i0 = t << 4;

  // ---- stage f-tile into LDS (256 floats) ----
  if (tid < 256)
    f_lds[tid] = f2[(((size_t)(b << 10) + (t << 4)) << 4) + tid];
  __syncthreads();

  const float LOG2E = 1.4426950408889634f;
  float w2s[16];
  float K;
  {
    float sw = 0.f;
#pragma unroll
    for (int a = 0; a < 16; ++a) {
      float v = w2[a];
      w2s[a] = v * (2.f * LOG2E);
      sw += v;
    }
    K = (sw + b2[0]) * LOG2E;
  }
  const float4* fl4 = reinterpret_cast<const float4*>(&f_lds[0]);

  // ---- phase 1: wave wv computes chunks wv, wv+8 (if < nch) ----
  for (int cc = wv; cc < nch; cc += 8) {
    const float4* gp = reinterpret_cast<const float4*>(
        g2 + ((size_t)((b << 10) + (cc << 6) + lane) << 4));
    float4 g0 = gp[0], g1 = gp[1], g2v = gp[2], g3 = gp[3];
    float gr[16] = {g0.x,  g0.y,  g0.z,  g0.w,  g1.x,  g1.y,  g1.z,  g1.w,
                    g2v.x, g2v.y, g2v.z, g2v.w, g3.x,  g3.y,  g3.z,  g3.w};
    char* esbase = reinterpret_cast<char*>(&esb[cc][0]);
    const int jglob = (cc << 6) + lane;
    const int jx2 = lane << 1;
#pragma unroll
    for (int i = 0; i < 16; ++i) {
      float4 fa = fl4[(i << 2) + 0], fb = fl4[(i << 2) + 1];
      float4 fc = fl4[(i << 2) + 2], fd = fl4[(i << 2) + 3];
      float frv[16] = {fa.x, fa.y, fa.z, fa.w, fb.x, fb.y, fb.z, fb.w,
                       fc.x, fc.y, fc.z, fc.w, fd.x, fd.y, fd.z, fd.w};
      float ps0 = 0.f, ps1 = 0.f;
#define TERM(idx, dst)                                                   \
  dst = fmaf(w2s[idx],                                                   \
             __builtin_amdgcn_rcpf(fmaf(frv[idx], gr[idx], 1.0f)),       \
             dst);
      TERM(0, ps0)  TERM(1, ps0)  TERM(2, ps0)  TERM(3, ps0)
      TERM(4, ps0)  TERM(5, ps0)  TERM(6, ps0)  TERM(7, ps0)
      TERM(8, ps1)  TERM(9, ps1)  TERM(10, ps1) TERM(11, ps1)
      TERM(12, ps1) TERM(13, ps1) TERM(14, ps1) TERM(15, ps1)
#undef TERM
      float ev =
          (jglob < i0 + i) ? __builtin_amdgcn_exp2f(K - (ps0 + ps1)) : 0.f;
      *reinterpret_cast<unsigned short*>(
          esbase + (((i << 7) + jx2) ^ ((i & 7) << 4))) = bf16_rne(ev);
    }
  }
  __syncthreads();  // all nch e tiles visible

  // ---- phase 2: wave wv owns cols [wv*16,+16) of the tile ----
  {
    const int nt = wv;
    const int li = lane & 15;
    const int g = lane >> 4;
    const int cxor = (li & 7) << 4;
    const int off0 = ((li << 7) + (g << 4)) ^ cxor;       // k-tile 0 (j 0..31)
    const int off1 = ((li << 7) + 64 + (g << 4)) ^ cxor;  // k-tile 1 (j 32..63)

    f32x4v acc = (f32x4v){0.f, 0.f, 0.f, 0.f};
    f32x4v accD = (f32x4v){0.f, 0.f, 0.f, 0.f};
    bf16x8 ones;
#pragma unroll
    for (int e = 0; e < 8; ++e) ones[e] = (short)0x3F80;  // bf16(1.0)

    const bf16x8* xfb =
        reinterpret_cast<const bf16x8*>(xfrag) + ((size_t)(b << 5) << 9) + lane;
    for (int cc = 0; cc < nch; ++cc) {
      const char* eb = reinterpret_cast<const char*>(&esb[cc][0]);
      bf16x8 a0 = *reinterpret_cast<const bf16x8*>(eb + off0);
      bf16x8 a1 = *reinterpret_cast<const bf16x8*>(eb + off1);
      const bf16x8* xf = xfb + ((size_t)(cc << 1) << 9);
      bf16x8 bf0 = xf[(size_t)(nt << 6)];
      bf16x8 bf1 = xf[(size_t)(nt << 6) + 512];
      acc = __builtin_amdgcn_mfma_f32_16x16x32_bf16(a0, bf0, acc, 0, 0, 0);
      acc = __builtin_amdgcn_mfma_f32_16x16x32_bf16(a1, bf1, acc, 0, 0, 0);
      accD = __builtin_amdgcn_mfma_f32_16x16x32_bf16(a0, ones, accD, 0, 0, 0);
      accD = __builtin_amdgcn_mfma_f32_16x16x32_bf16(a1, ones, accD, 0, 0, 0);
    }

    float* op = out + ((size_t)((b << 10) + (t << 4)) << 7) + (nt << 4) + li;
#pragma unroll
    for (int rr = 0; rr < 4; ++rr)
      op[(size_t)((g << 2) + rr) << 7] = acc[rr] / (accD[rr] + 1e-10f);
  }
}

// ---------------- fallback: monolithic kernel (factorized math) ------------
#define JC 64
__global__ __launch_bounds__(256) void attn_kernel_mono(
    const float* __restrict__ x, const float* __restrict__ f2,
    const float* __restrict__ g2, const float* __restrict__ w2,
    const float* __restrict__ b2, float* __restrict__ out) {
  __shared__ __align__(16) float xs[JC * H_];
  __shared__ __align__(16) float gsm[JC * 18];
  __shared__ __align__(16) float es2[JC * A_];
  __shared__ float dpart[4][16];
  __shared__ float denom[16];

  const int tid = threadIdx.x;
  const int bid = blockIdx.x;
  const int tile = 63 - (bid >> 3);
  const int b = bid & 7;
  const int i0 = tile * 16;

  const float LOG2E = 1.4426950408889634f;
  float w2s[16];
  float K;
  {
    float sw = 0.f;
#pragma unroll
    for (int a = 0; a < 16; ++a) {
      float v = w2[a];
      w2s[a] = v * (2.f * LOG2E);
      sw += v;
    }
    K = (sw + b2[0]) * LOG2E;
  }

  const int ti_e = tid & 15;
  const int jq = tid >> 4;
  float f_reg[16];
  {
    const float* frow = f2 + (size_t)((b << 10) + i0 + ti_e) * A_;
#pragma unroll
    for (int a = 0; a < 16; ++a) f_reg[a] = frow[a];
  }

  const int hc = tid & 31;
  const int jg = tid >> 5;
  float4 acc[16];
#pragma unroll
  for (int t = 0; t < 16; ++t) acc[t] = make_float4(0.f, 0.f, 0.f, 0.f);
  if (tid < 16) denom[tid] = 0.f;

  const int nch = (i0 + 15 + JC - 1) / JC;
  float4* xs4 = reinterpret_cast<float4*>(xs);
  const float4* es4 = reinterpret_cast<const float4*>(es2);
  const float4* xg4 = reinterpret_cast<const float4*>(x + (size_t)(b << 10) * H_);

  for (int c = 0; c < nch; ++c) {
    const int jbase = c * JC;
    __syncthreads();
    const float4* src = xg4 + jbase * (H_ / 4);
#pragma unroll
    for (int t = 0; t < 8; ++t) xs4[tid + 256 * t] = src[tid + 256 * t];
    {
      const float4* g4p =
          reinterpret_cast<const float4*>(g2 + (size_t)((b << 10) + jbase) * A_);
      float4 g4 = g4p[tid];
      float* dst = gsm + (tid >> 2) * 18 + (tid & 3) * 4;
      dst[0] = g4.x; dst[1] = g4.y; dst[2] = g4.z; dst[3] = g4.w;
    }
    __syncthreads();

    float partial = 0.f;
#pragma unroll
    for (int k = 0; k < 4; ++k) {
      const int jl = jq * 4 + k;
      const int j = jbase + jl;
      const float* grow = gsm + jl * 18;
      float ps = 0.f;
#pragma unroll
      for (int a = 0; a < 16; ++a) {
        float rr = __builtin_amdgcn_rcpf(fmaf(f_reg[a], grow[a], 1.0f));
        ps = fmaf(w2s[a], rr, ps);
      }
      float ev = (j < i0 + ti_e) ? __builtin_amdgcn_exp2f(K - ps) : 0.f;
      es2[jl * A_ + ti_e] = ev;
      partial += ev;
    }
    partial += __shfl_xor(partial, 16);
    partial += __shfl_xor(partial, 32);
    if ((tid & 63) < 16) dpart[tid >> 6][ti_e] = partial;
    __syncthreads();
    if (tid < 16)
      denom[tid] += dpart[0][tid] + dpart[1][tid] + dpart[2][tid] + dpart[3][tid];

#pragma unroll 2
    for (int jj = 0; jj < 8; ++jj) {
      const int jl = jg * 8 + jj;
      float4 xv = xs4[jl * (H_ / 4) + hc];
      float4 e0 = es4[jl * 4 + 0];
      float4 e1 = es4[jl * 4 + 1];
      float4 e2v = es4[jl * 4 + 2];
      float4 e3 = es4[jl * 4 + 3];
#define FMA4_(AC, sc)                \
  AC.x = fmaf(sc, xv.x, AC.x);       \
  AC.y = fmaf(sc, xv.y, AC.y);       \
  AC.z = fmaf(sc, xv.z, AC.z);       \
  AC.w = fmaf(sc, xv.w, AC.w)
      FMA4_(acc[0], e0.x);  FMA4_(acc[1], e0.y);
      FMA4_(acc[2], e0.z);  FMA4_(acc[3], e0.w);
      FMA4_(acc[4], e1.x);  FMA4_(acc[5], e1.y);
      FMA4_(acc[6], e1.z);  FMA4_(acc[7], e1.w);
      FMA4_(acc[8], e2v.x); FMA4_(acc[9], e2v.y);
      FMA4_(acc[10], e2v.z); FMA4_(acc[11], e2v.w);
      FMA4_(acc[12], e3.x); FMA4_(acc[13], e3.y);
      FMA4_(acc[14], e3.z); FMA4_(acc[15], e3.w);
#undef FMA4_
    }
  }

  __syncthreads();
  float4* red4 = xs4;
  if (jg >= 4) {
#pragma unroll
    for (int t = 0; t < 16; ++t) red4[((jg - 4) * 16 + t) * 32 + hc] = acc[t];
  }
  __syncthreads();
  if (jg < 4) {
#pragma unroll
    for (int t = 0; t < 16; ++t) {
      float4 v = red4[(jg * 16 + t) * 32 + hc];
      acc[t].x += v.x; acc[t].y += v.y; acc[t].z += v.z; acc[t].w += v.w;
    }
  }
  __syncthreads();
  if (jg == 2 || jg == 3) {
#pragma unroll
    for (int t = 0; t < 16; ++t) red4[((jg - 2) * 16 + t) * 32 + hc] = acc[t];
  }
  __syncthreads();
  if (jg < 2) {
#pragma unroll
    for (int t = 0; t < 16; ++t) {
      float4 v = red4[(jg * 16 + t) * 32 + hc];
      acc[t].x += v.x; acc[t].y += v.y; acc[t].z += v.z; acc[t].w += v.w;
    }
  }
  __syncthreads();
  if (jg == 1) {
#pragma unroll
    for (int t = 0; t < 16; ++t) red4[t * 32 + hc] = acc[t];
  }
  __syncthreads();
  if (jg == 0) {
    float4* out4 = reinterpret_cast<float4*>(out);
#pragma unroll
    for (int t = 0; t < 16; ++t) {
      float4 v = red4[t * 32 + hc];
      float dn = 1.0f / (denom[t] + 1e-10f);
      float4 o;
      o.x = (acc[t].x + v.x) * dn;
      o.y = (acc[t].y + v.y) * dn;
      o.z = (acc[t].z + v.z) * dn;
      o.w = (acc[t].w + v.w) * dn;
      out4[(size_t)((b << 10) + i0 + t) * 32 + hc] = o;
    }
  }
}

extern "C" void kernel_launch(void* const* d_in, const int* in_sizes, int n_in,
                              void* d_out, int out_size, void* d_ws,
                              size_t ws_size, hipStream_t stream) {
  (void)in_sizes; (void)n_in; (void)out_size;
  const float* x  = (const float*)d_in[0];
  const float* W1 = (const float*)d_in[1];
  const float* b1 = (const float*)d_in[2];
  const float* w2 = (const float*)d_in[3];
  const float* b2 = (const float*)d_in[4];
  float* out = (float*)d_out;

  float* f2 = (float*)d_ws;                  // [B*S, A]  F = exp2 domain
  float* g2 = f2 + (size_t)B_ * S_ * A_;     // [B*S, A]  E = exp2 domain
  unsigned short* xfrag = (unsigned short*)(g2 + (size_t)B_ * S_ * A_);

  const size_t need_fused =
      ((size_t)B_ * S_ * A_ * 2 + 524288 /*xfrag as float-equivalents*/) *
      sizeof(float);

  if (ws_size >= need_fused) {
    prep_kernel<<<B_ * S_ / 8, 256, 0, stream>>>(x, W1, b1, f2, g2, xfrag);
    attn_fused7<<<512, 512, 0, stream>>>(f2, g2, xfrag, w2, b2, out);
  } else {
    prep_kernel<<<B_ * S_ / 8, 256, 0, stream>>>(x, W1, b1, f2, g2,
                                                 (unsigned short*)f2 /*dummy*/);
    attn_kernel_mono<<<B_ * 64, 256, 0, stream>>>(x, f2, g2, w2, b2, out);
  }
}

// Round 21
// 29.184 us; speedup vs baseline: 4.2757x; 2.6690x over previous
//
#include <hip/hip_runtime.h>

// ConcatenationAttention: B=8, S=1024, H=128, A=16
// out[b,i,:] = sum_{j<i} w_ij * x[b,j,:],  w = softmax over j of
//   score(i,j) = sum_a w2[a]*tanh(f[b,i,a] + g[b,j,a] + b1[a]) + b2
//
// Round 21: REVERT to round-18 (best: 29.3 us). 256 blocks x 1024 threads,
// tiles paired to exactly 17 chunks; phase 1 straight-line (chunk wv + coop
// chunk 16); phase 2: disjoint 16x16 C-fragments, MFMA numerator + ones-MFMA
// denominator. prep fuses f/g projection + xfrag packing.

#define B_ 8
#define S_ 1024
#define H_ 128
#define A_ 16

typedef float f32x4v __attribute__((ext_vector_type(4)));
typedef short bf16x8 __attribute__((ext_vector_type(8)));

__device__ __forceinline__ unsigned short bf16_rne(float v) {
  unsigned u = __float_as_uint(v);
  u += 0x7FFFu + ((u >> 16) & 1u);
  return (unsigned short)(u >> 16);
}

// Fused prep: f/g projection (exp2 domain) + xfrag bf16 B-fragment packing.
// Block owns 8 consecutive rows (one (jt,sub) slice of xfrag).
__global__ __launch_bounds__(256) void prep_kernel(
    const float* __restrict__ x, const float* __restrict__ W1,
    const float* __restrict__ b1, float* __restrict__ f2,
    float* __restrict__ g2, unsigned short* __restrict__ xfrag) {
  __shared__ __align__(16) float xls[8 * H_];  // 4 KB
  const int tid = threadIdx.x;
  const int row0 = blockIdx.x * 8;
  reinterpret_cast<float4*>(xls)[tid] =
      reinterpret_cast<const float4*>(x + (size_t)row0 * H_)[tid];
  __syncthreads();

  // ---- f/g: 8 rows x 32 (16 a x 2 half) ----
  {
    const int r = tid >> 5;
    const int q = tid & 31;
    const int a = q & 15;
    const int half = q >> 4;
    const float4* xr4 = reinterpret_cast<const float4*>(xls + r * H_);
    const float* w = W1 + half * H_ * A_ + a;
    float s = 0.f;
#pragma unroll 4
    for (int hi = 0; hi < H_ / 4; ++hi) {
      float4 xv = xr4[hi];
      s = fmaf(xv.x, w[(hi * 4 + 0) * A_], s);
      s = fmaf(xv.y, w[(hi * 4 + 1) * A_], s);
      s = fmaf(xv.z, w[(hi * 4 + 2) * A_], s);
      s = fmaf(xv.w, w[(hi * 4 + 3) * A_], s);
    }
    const float TANH_C = 2.8853900817779268f;   // 2*log2(e)
    const int row = row0 + r;
    if (half == 0)
      f2[row * A_ + a] = __builtin_amdgcn_exp2f((s + b1[a]) * TANH_C);
    else
      g2[row * A_ + a] = __builtin_amdgcn_exp2f(s * TANH_C);
  }

  // ---- xfrag: threads 0..127 pack col (nt*16+li) of all 8 rows ----
  if (tid < 128) {
    const int nt = tid >> 4;
    const int li = tid & 15;
    const int col = (nt << 4) + li;
    const int b = row0 >> 10;
    const int j0 = row0 & 1023;
    const int jt = j0 >> 5;
    const int sub = (j0 >> 3) & 3;
    union { unsigned short u[8]; uint4 v; } rr;
#pragma unroll
    for (int e = 0; e < 8; ++e) rr.u[e] = bf16_rne(xls[e * H_ + col]);
    reinterpret_cast<uint4*>(
        xfrag)[(((size_t)((b << 5) + jt) * 8 + nt) << 6) + (sub << 4) + li] =
        rr.v;
  }
}

// -------- fused attention (round-18 proven version) ------------------------
__global__ __launch_bounds__(1024, 4) void attn_fused5(
    const float* __restrict__ f2, const float* __restrict__ g2,
    const unsigned short* __restrict__ xfrag, const float* __restrict__ w2,
    const float* __restrict__ b2, float* __restrict__ out) {
  __shared__ __align__(16) unsigned short esb[17][1024];  // 34 KB
  __shared__ __align__(16) float f_lds[512];              // 2 KB (2 f-tiles)

  const int tid = threadIdx.x;
  const int wv = tid >> 6;
  const int lane = tid & 63;
  const int bid = blockIdx.x;
  const int b = bid & 7;
  const int blk = bid >> 3;       // [0,32)
  const int p = blk >> 2;         // pair index [0,8)
  const int u = blk & 3;
  const int tile1 = (15 - p) * 4 + u;  // nch1 = 16-p
  const int tile2 = p * 4 + u;         // nch2 = p+1 ; nch1+nch2 = 17
  const int nch1 = 16 - p;

  // ---- hoisted g loads: issue BEFORE the f-staging barrier ----
  const int tisel = (wv < nch1) ? 0 : 1;
  const int tA = tisel ? tile2 : tile1;
  const int cA = tisel ? (wv - nch1) : wv;
  const int i0A = tA << 4;
  const int jbaseA = cA << 6;
  const float4* gpA = reinterpret_cast<const float4*>(
      g2 + ((size_t)((b << 10) + jbaseA + lane) << 4));
  float4 gA0 = gpA[0], gA1 = gpA[1], gA2 = gpA[2], gA3 = gpA[3];
  const int jbaseB = p << 6;  // phase-1b chunk (tile2, c=p)
  const float4* gpB = reinterpret_cast<const float4*>(
      g2 + ((size_t)((b << 10) + jbaseB + lane) << 4));
  float4 gB0 = gpB[0], gB1 = gpB[1], gB2 = gpB[2], gB3 = gpB[3];

  // ---- stage f-tiles into LDS (coalesced, 512 floats) ----
  if (tid < 512) {
    const int tsel = tid >> 8;
    const int trow = tsel ? tile2 : tile1;
    f_lds[tid] = f2[(((size_t)(b << 10) + (trow << 4)) << 4) + (tid & 255)];
  }
  __syncthreads();

  const float LOG2E = 1.4426950408889634f;
  float w2s[16];
  float K;
  {
    float sw = 0.f;
#pragma unroll
    for (int a = 0; a < 16; ++a) {
      float v = w2[a];
      w2s[a] = v * (2.f * LOG2E);
      sw += v;
    }
    K = (sw + b2[0]) * LOG2E;
  }

  // ---- phase 1a: this wave's own chunk (cc = wv) ----
  {
    float gr[16] = {gA0.x, gA0.y, gA0.z, gA0.w, gA1.x, gA1.y, gA1.z, gA1.w,
                    gA2.x, gA2.y, gA2.z, gA2.w, gA3.x, gA3.y, gA3.z, gA3.w};
    char* esbase = reinterpret_cast<char*>(&esb[wv][0]);
    const float4* fl4 = reinterpret_cast<const float4*>(&f_lds[tisel << 8]);
    const int jglob = jbaseA + lane;
    const int jx2 = lane << 1;
#pragma unroll
    for (int i = 0; i < 16; ++i) {
      float4 fa = fl4[(i << 2) + 0], fb = fl4[(i << 2) + 1];
      float4 fc = fl4[(i << 2) + 2], fd = fl4[(i << 2) + 3];
      float frv[16] = {fa.x, fa.y, fa.z, fa.w, fb.x, fb.y, fb.z, fb.w,
                       fc.x, fc.y, fc.z, fc.w, fd.x, fd.y, fd.z, fd.w};
      float ps0 = 0.f, ps1 = 0.f;
#define TERM(idx, dst)                                                   \
  dst = fmaf(w2s[idx],                                                   \
             __builtin_amdgcn_rcpf(fmaf(frv[idx], gr[idx], 1.0f)),       \
             dst);
      TERM(0, ps0)  TERM(1, ps0)  TERM(2, ps0)  TERM(3, ps0)
      TERM(4, ps0)  TERM(5, ps0)  TERM(6, ps0)  TERM(7, ps0)
      TERM(8, ps1)  TERM(9, ps1)  TERM(10, ps1) TERM(11, ps1)
      TERM(12, ps1) TERM(13, ps1) TERM(14, ps1) TERM(15, ps1)
      float ev =
          (jglob < i0A + i) ? __builtin_amdgcn_exp2f(K - (ps0 + ps1)) : 0.f;
      *reinterpret_cast<unsigned short*>(
          esbase + (((i << 7) + jx2) ^ ((i & 7) << 4))) = bf16_rne(ev);
    }
  }

  // ---- phase 1b: chunk 16 (tile2, c=p), wave wv computes row i=wv ----
  {
    float gr[16] = {gB0.x, gB0.y, gB0.z, gB0.w, gB1.x, gB1.y, gB1.z, gB1.w,
                    gB2.x, gB2.y, gB2.z, gB2.w, gB3.x, gB3.y, gB3.z, gB3.w};
    char* esbase = reinterpret_cast<char*>(&esb[16][0]);
    const float4* fl4 = reinterpret_cast<const float4*>(&f_lds[256]);
    const int i = wv;
    float4 fa = fl4[(i << 2) + 0], fb = fl4[(i << 2) + 1];
    float4 fc = fl4[(i << 2) + 2], fd = fl4[(i << 2) + 3];
    float frv[16] = {fa.x, fa.y, fa.z, fa.w, fb.x, fb.y, fb.z, fb.w,
                     fc.x, fc.y, fc.z, fc.w, fd.x, fd.y, fd.z, fd.w};
    float ps0 = 0.f, ps1 = 0.f;
    TERM(0, ps0)  TERM(1, ps0)  TERM(2, ps0)  TERM(3, ps0)
    TERM(4, ps0)  TERM(5, ps0)  TERM(6, ps0)  TERM(7, ps0)
    TERM(8, ps1)  TERM(9, ps1)  TERM(10, ps1) TERM(11, ps1)
    TERM(12, ps1) TERM(13, ps1) TERM(14, ps1) TERM(15, ps1)
#undef TERM
    float ev = ((jbaseB + lane) < (tile2 << 4) + i)
                   ? __builtin_amdgcn_exp2f(K - (ps0 + ps1))
                   : 0.f;
    *reinterpret_cast<unsigned short*>(
        esbase + (((i << 7) + (lane << 1)) ^ ((i & 7) << 4))) = bf16_rne(ev);
  }
  __syncthreads();  // all 17 e tiles visible

  // ---- phase 2: wave (ti2, nt) owns output rows [t2*16,+16) cols [nt*16,+16)
  {
    const int ti2 = wv >> 3;
    const int nt = wv & 7;
    const int t2 = ti2 ? tile2 : tile1;
    const int ccs = ti2 ? nch1 : 0;
    const int cce = ti2 ? 17 : nch1;

    const int li = lane & 15;
    const int g = lane >> 4;
    const int cxor = (li & 7) << 4;
    const int off0 = ((li << 7) + (g << 4)) ^ cxor;       // k-tile 0 (j 0..31)
    const int off1 = ((li << 7) + 64 + (g << 4)) ^ cxor;  // k-tile 1 (j 32..63)

    f32x4v acc = (f32x4v){0.f, 0.f, 0.f, 0.f};
    f32x4v accD = (f32x4v){0.f, 0.f, 0.f, 0.f};
    bf16x8 ones;
#pragma unroll
    for (int e = 0; e < 8; ++e) ones[e] = (short)0x3F80;  // bf16(1.0)

    const bf16x8* xfb =
        reinterpret_cast<const bf16x8*>(xfrag) + ((size_t)(b << 5) << 9) + lane;
    for (int cc = ccs; cc < cce; ++cc) {
      const int c2 = cc - ccs;  // j-chunk within tile
      const char* eb = reinterpret_cast<const char*>(&esb[cc][0]);
      bf16x8 a0 = *reinterpret_cast<const bf16x8*>(eb + off0);
      bf16x8 a1 = *reinterpret_cast<const bf16x8*>(eb + off1);
      const bf16x8* xf = xfb + ((size_t)(c2 << 1) << 9);
      bf16x8 bf0 = xf[(size_t)(nt << 6)];
      bf16x8 bf1 = xf[(size_t)(nt << 6) + 512];
      acc = __builtin_amdgcn_mfma_f32_16x16x32_bf16(a0, bf0, acc, 0, 0, 0);
      acc = __builtin_amdgcn_mfma_f32_16x16x32_bf16(a1, bf1, acc, 0, 0, 0);
      accD = __builtin_amdgcn_mfma_f32_16x16x32_bf16(a0, ones, accD, 0, 0, 0);
      accD = __builtin_amdgcn_mfma_f32_16x16x32_bf16(a1, ones, accD, 0, 0, 0);
    }

    float* op = out + ((size_t)((b << 10) + (t2 << 4)) << 7) + (nt << 4) + li;
#pragma unroll
    for (int rr = 0; rr < 4; ++rr)
      op[(size_t)((g << 2) + rr) << 7] = acc[rr] / (accD[rr] + 1e-10f);
  }
}

// ---------------- fallback: monolithic kernel (factorized math) ------------
#define JC 64
__global__ __launch_bounds__(256) void attn_kernel_mono(
    const float* __restrict__ x, const float* __restrict__ f2,
    const float* __restrict__ g2, const float* __restrict__ w2,
    const float* __restrict__ b2, float* __restrict__ out) {
  __shared__ __align__(16) float xs[JC * H_];
  __shared__ __align__(16) float gsm[JC * 18];
  __shared__ __align__(16) float es2[JC * A_];
  __shared__ float dpart[4][16];
  __shared__ float denom[16];

  const int tid = threadIdx.x;
  const int bid = blockIdx.x;
  const int tile = 63 - (bid >> 3);
  const int b = bid & 7;
  const int i0 = tile * 16;

  const float LOG2E = 1.4426950408889634f;
  float w2s[16];
  float K;
  {
    float sw = 0.f;
#pragma unroll
    for (int a = 0; a < 16; ++a) {
      float v = w2[a];
      w2s[a] = v * (2.f * LOG2E);
      sw += v;
    }
    K = (sw + b2[0]) * LOG2E;
  }

  const int ti_e = tid & 15;
  const int jq = tid >> 4;
  float f_reg[16];
  {
    const float* frow = f2 + (size_t)((b << 10) + i0 + ti_e) * A_;
#pragma unroll
    for (int a = 0; a < 16; ++a) f_reg[a] = frow[a];
  }

  const int hc = tid & 31;
  const int jg = tid >> 5;
  float4 acc[16];
#pragma unroll
  for (int t = 0; t < 16; ++t) acc[t] = make_float4(0.f, 0.f, 0.f, 0.f);
  if (tid < 16) denom[tid] = 0.f;

  const int nch = (i0 + 15 + JC - 1) / JC;
  float4* xs4 = reinterpret_cast<float4*>(xs);
  const float4* es4 = reinterpret_cast<const float4*>(es2);
  const float4* xg4 = reinterpret_cast<const float4*>(x + (size_t)(b << 10) * H_);

  for (int c = 0; c < nch; ++c) {
    const int jbase = c * JC;
    __syncthreads();
    const float4* src = xg4 + jbase * (H_ / 4);
#pragma unroll
    for (int t = 0; t < 8; ++t) xs4[tid + 256 * t] = src[tid + 256 * t];
    {
      const float4* g4p =
          reinterpret_cast<const float4*>(g2 + (size_t)((b << 10) + jbase) * A_);
      float4 g4 = g4p[tid];
      float* dst = gsm + (tid >> 2) * 18 + (tid & 3) * 4;
      dst[0] = g4.x; dst[1] = g4.y; dst[2] = g4.z; dst[3] = g4.w;
    }
    __syncthreads();

    float partial = 0.f;
#pragma unroll
    for (int k = 0; k < 4; ++k) {
      const int jl = jq * 4 + k;
      const int j = jbase + jl;
      const float* grow = gsm + jl * 18;
      float ps = 0.f;
#pragma unroll
      for (int a = 0; a < 16; ++a) {
        float rr = __builtin_amdgcn_rcpf(fmaf(f_reg[a], grow[a], 1.0f));
        ps = fmaf(w2s[a], rr, ps);
      }
      float ev = (j < i0 + ti_e) ? __builtin_amdgcn_exp2f(K - ps) : 0.f;
      es2[jl * A_ + ti_e] = ev;
      partial += ev;
    }
    partial += __shfl_xor(partial, 16);
    partial += __shfl_xor(partial, 32);
    if ((tid & 63) < 16) dpart[tid >> 6][ti_e] = partial;
    __syncthreads();
    if (tid < 16)
      denom[tid] += dpart[0][tid] + dpart[1][tid] + dpart[2][tid] + dpart[3][tid];

#pragma unroll 2
    for (int jj = 0; jj < 8; ++jj) {
      const int jl = jg * 8 + jj;
      float4 xv = xs4[jl * (H_ / 4) + hc];
      float4 e0 = es4[jl * 4 + 0];
      float4 e1 = es4[jl * 4 + 1];
      float4 e2v = es4[jl * 4 + 2];
      float4 e3 = es4[jl * 4 + 3];
#define FMA4_(AC, sc)                \
  AC.x = fmaf(sc, xv.x, AC.x);       \
  AC.y = fmaf(sc, xv.y, AC.y);       \
  AC.z = fmaf(sc, xv.z, AC.z);       \
  AC.w = fmaf(sc, xv.w, AC.w)
      FMA4_(acc[0], e0.x);  FMA4_(acc[1], e0.y);
      FMA4_(acc[2], e0.z);  FMA4_(acc[3], e0.w);
      FMA4_(acc[4], e1.x);  FMA4_(acc[5], e1.y);
      FMA4_(acc[6], e1.z);  FMA4_(acc[7], e1.w);
      FMA4_(acc[8], e2v.x); FMA4_(acc[9], e2v.y);
      FMA4_(acc[10], e2v.z); FMA4_(acc[11], e2v.w);
      FMA4_(acc[12], e3.x); FMA4_(acc[13], e3.y);
      FMA4_(acc[14], e3.z); FMA4_(acc[15], e3.w);
#undef FMA4_
    }
  }

  __syncthreads();
  float4* red4 = xs4;
  if (jg >= 4) {
#pragma unroll
    for (int t = 0; t < 16; ++t) red4[((jg - 4) * 16 + t) * 32 + hc] = acc[t];
  }
  __syncthreads();
  if (jg < 4) {
#pragma unroll
    for (int t = 0; t < 16; ++t) {
      float4 v = red4[(jg * 16 + t) * 32 + hc];
      acc[t].x += v.x; acc[t].y += v.y; acc[t].z += v.z; acc[t].w += v.w;
    }
  }
  __syncthreads();
  if (jg == 2 || jg == 3) {
#pragma unroll
    for (int t = 0; t < 16; ++t) red4[((jg - 2) * 16 + t) * 32 + hc] = acc[t];
  }
  __syncthreads();
  if (jg < 2) {
#pragma unroll
    for (int t = 0; t < 16; ++t) {
      float4 v = red4[(jg * 16 + t) * 32 + hc];
      acc[t].x += v.x; acc[t].y += v.y; acc[t].z += v.z; acc[t].w += v.w;
    }
  }
  __syncthreads();
  if (jg == 1) {
#pragma unroll
    for (int t = 0; t < 16; ++t) red4[t * 32 + hc] = acc[t];
  }
  __syncthreads();
  if (jg == 0) {
    float4* out4 = reinterpret_cast<float4*>(out);
#pragma unroll
    for (int t = 0; t < 16; ++t) {
      float4 v = red4[t * 32 + hc];
      float dn = 1.0f / (denom[t] + 1e-10f);
      float4 o;
      o.x = (acc[t].x + v.x) * dn;
      o.y = (acc[t].y + v.y) * dn;
      o.z = (acc[t].z + v.z) * dn;
      o.w = (acc[t].w + v.w) * dn;
      out4[(size_t)((b << 10) + i0 + t) * 32 + hc] = o;
    }
  }
}

extern "C" void kernel_launch(void* const* d_in, const int* in_sizes, int n_in,
                              void* d_out, int out_size, void* d_ws,
                              size_t ws_size, hipStream_t stream) {
  (void)in_sizes; (void)n_in; (void)out_size;
  const float* x  = (const float*)d_in[0];
  const float* W1 = (const float*)d_in[1];
  const float* b1 = (const float*)d_in[2];
  const float* w2 = (const float*)d_in[3];
  const float* b2 = (const float*)d_in[4];
  float* out = (float*)d_out;

  float* f2 = (float*)d_ws;                  // [B*S, A]  F = exp2 domain
  float* g2 = f2 + (size_t)B_ * S_ * A_;     // [B*S, A]  E = exp2 domain
  unsigned short* xfrag = (unsigned short*)(g2 + (size_t)B_ * S_ * A_);

  const size_t need_fused =
      ((size_t)B_ * S_ * A_ * 2 + 524288 /*xfrag as float-equivalents*/) *
      sizeof(float);

  if (ws_size >= need_fused) {
    prep_kernel<<<B_ * S_ / 8, 256, 0, stream>>>(x, W1, b1, f2, g2, xfrag);
    attn_fused5<<<256, 1024, 0, stream>>>(f2, g2, xfrag, w2, b2, out);
  } else {
    prep_kernel<<<B_ * S_ / 8, 256, 0, stream>>>(x, W1, b1, f2, g2,
                                                 (unsigned short*)f2 /*dummy*/);
    attn_kernel_mono<<<B_ * 64, 256, 0, stream>>>(x, f2, g2, w2, b2, out);
  }
}